// Round 9
// baseline (198.353 us; speedup 1.0000x reference)
//
#include <hip/hip_runtime.h>
#include <hip/hip_fp16.h>
#include <math.h>

// PhysicsResidual via 2nd-order forward-mode AD, split-fp16 MFMA, operand-swapped.
// State per point: 6 vectors of 128 (h, 4 first derivs, q = signed 2nd-deriv combo).
// Per layer GEMM (per 16-pt group): A = W (M=128 neurons), B = X^T (N = 6v*16p = 96),
// K = 128. Split-fp16: A*B ~= Wh*Xh + Wh*Xl + Wl*Xh (fp32 MFMA acc).
// Fragment maps (validated R3/R4): arg0 row = lane&15, arg1 col = lane&15,
// k = (lane>>4)*8 + e; D: col = lane&15 (=point), row = (lane>>4)*4 + reg (=neuron).
//
// R9: SPLIT-PHASE. TPB=512 = 2 groups x 4 waves, each group owns 16 points + its own
// X buffers. Groups are phase-shifted by one segment: every barrier interval has one
// group doing GEMM (MFMA+LDS-read) and the other doing epilogue (VALU+LDS-write).
// Waves w and w+4 share a SIMD -> MFMA and VALU pipes both fed every interval.
// (R8 counters: MfmaUtil 48 + VALUBusy 46, both half-idle = phase serialization.)
// LDS 105KB -> 1 block/CU, 8 waves. NO cross-ks A-frag hoist (R6 spilled).

typedef _Float16 f16x8 __attribute__((ext_vector_type(8)));
typedef _Float16 f16x4 __attribute__((ext_vector_type(4)));
typedef _Float16 f16x2 __attribute__((ext_vector_type(2)));
typedef float    f32x4 __attribute__((ext_vector_type(4)));

constexpr int TPB  = 512;   // 8 waves = 2 groups x 4
constexpr int PG   = 16;    // points per group
constexpr int NG   = 2;     // groups per block
constexpr int PB   = PG * NG; // 32 points per block
constexpr int H    = 128;
constexpr int XPAD = 136;   // halves per padded X row (272 B, 16B-aligned)
constexpr int NV   = 6;
// pre-split W plane: 5 layers x 8 mt x 4 ks x 64 lanes x 8 halves
constexpr int WFRAG_HALVES = 5 * 8 * 4 * 64 * 8;           // 81920 halves
constexpr size_t WS_NEEDED = 2 * WFRAG_HALVES * sizeof(_Float16); // 327680 B

__device__ __forceinline__ float fast_tanh(float v) {
    float e = __expf(-2.0f * fabsf(v));
    float r = __builtin_amdgcn_rcpf(1.0f + e);
    return copysignf((1.0f - e) * r, v);
}

__device__ __forceinline__ f16x2 pkrtz(float a, float b) {
    return __builtin_bit_cast(f16x2, __builtin_amdgcn_cvt_pkrtz(a, b));
}

// ---------------- pre-split kernel: W1..W5 -> fp16 hi/lo fragments -----------
__global__ __launch_bounds__(256) void presplit_w(
    const float* __restrict__ W1, const float* __restrict__ W2,
    const float* __restrict__ W3, const float* __restrict__ W4,
    const float* __restrict__ W5, _Float16* __restrict__ whi,
    _Float16* __restrict__ wlo)
{
    const int gid = blockIdx.x * 256 + threadIdx.x;   // 0..10239
    const float* Ws[5] = { W1, W2, W3, W4, W5 };
    const int lane = gid & 63;
    const int rest = gid >> 6;        // 0..159
    const int ks   = rest & 3;
    const int mt   = (rest >> 2) & 7;
    const int l    = rest >> 5;       // 0..4
    const int n    = mt * 16 + (lane & 15);
    const int k0   = ks * 32 + (lane >> 4) * 8;
    const float4 u0 = *(const float4*)&Ws[l][n * H + k0];
    const float4 u1 = *(const float4*)&Ws[l][n * H + k0 + 4];
    const float vv[8] = { u0.x, u0.y, u0.z, u0.w, u1.x, u1.y, u1.z, u1.w };
    f16x8 h, o;
    #pragma unroll
    for (int e = 0; e < 8; ++e) {
        _Float16 hh = (_Float16)vv[e];
        h[e] = hh;
        o[e] = (_Float16)(vv[e] - (float)hh);
    }
    *(f16x8*)&whi[gid * 8] = h;
    *(f16x8*)&wlo[gid * 8] = o;
}

// ---------------- main kernel ------------------------------------------------
__global__ __launch_bounds__(TPB, 2) void pinn_mfma6(
    const float* __restrict__ t, const float* __restrict__ x,
    const float* __restrict__ y, const float* __restrict__ z,
    const float* __restrict__ W0, const float* __restrict__ b0,
    const float* __restrict__ W1, const float* __restrict__ b1,
    const float* __restrict__ W2, const float* __restrict__ b2,
    const float* __restrict__ W3, const float* __restrict__ b3,
    const float* __restrict__ W4, const float* __restrict__ b4,
    const float* __restrict__ W5, const float* __restrict__ b5,
    const float* __restrict__ W6,
    const _Float16* __restrict__ whi, const _Float16* __restrict__ wlo,
    int use_pre, float* __restrict__ out, int N)
{
    __shared__ _Float16 sXhi[NG][NV * PG * XPAD];   // 2 x 26112 B
    __shared__ _Float16 sXlo[NG][NV * PG * XPAD];   // 2 x 26112 B
    __shared__ float    sRed[NG][4][PG];            // 512 B -> 104960 B total

    const int tid  = threadIdx.x;
    const int lane = tid & 63;
    const int wave = tid >> 6;     // 0..7
    const int g    = wave >> 2;    // group 0/1 (waves w, w+4 share a SIMD)
    const int wn   = wave & 3;     // wave-in-group: owns neuron tiles mt = wn*2 + nt
    const int l15  = lane & 15;
    const int l4   = lane >> 4;    // 0..3
    const int gb   = blockIdx.x * PB;

    _Float16* __restrict__ myXhi = &sXhi[g][0];
    _Float16* __restrict__ myXlo = &sXlo[g][0];

    // ---------------- layer 0 (input dim 4, analytic tangents) -------------
    {
        const int gt = tid & 255;         // thread-in-group
        const int p0 = gt >> 4;           // 0..15
        const int i0 = gt & 15;           // owns neurons i0*8 .. i0*8+7
        int gp = gb + g * PG + p0; if (gp >= N) gp = N - 1;
        const float pt0 = t[gp], pt1 = x[gp], pt2 = y[gp], pt3 = z[gp];
        float nv[NV][8];
        #pragma unroll
        for (int j = 0; j < 8; ++j) {
            const int i = i0 * 8 + j;
            const float4 wv = *(const float4*)&W0[i * 4];
            const float zv = fmaf(wv.x, pt0, fmaf(wv.y, pt1, fmaf(wv.z, pt2, fmaf(wv.w, pt3, b0[i]))));
            const float hv = fast_tanh(zv);
            const float s  = 1.0f - hv * hv;
            const float ssq = ((wv.x * wv.x - wv.y * wv.y) - wv.z * wv.z) - wv.w * wv.w;
            nv[0][j] = hv;       nv[1][j] = s * wv.x; nv[2][j] = s * wv.y;
            nv[3][j] = s * wv.z; nv[4][j] = s * wv.w; nv[5][j] = -2.0f * hv * s * ssq;
        }
        #pragma unroll
        for (int v = 0; v < NV; ++v) {
            f16x8 hh, oo;
            #pragma unroll
            for (int j = 0; j < 8; ++j) {
                _Float16 h_ = (_Float16)nv[v][j];
                hh[j] = h_;
                oo[j] = (_Float16)(nv[v][j] - (float)h_);
            }
            const int off = (v * PG + p0) * XPAD + i0 * 8;
            *(f16x8*)&myXhi[off] = hh;
            *(f16x8*)&myXlo[off] = oo;
        }
    }
    __syncthreads();

    // ---- phase-shifted segment loop: group g runs step u = s - g ----------
    // u even -> GEMM(l = u/2); u odd -> EPI(l). B idles at s=0, A at s=10.
    f32x4 acc[NV][2];

    for (int s = 0; s < 11; ++s) {
        const int u = s - g;
        if (u >= 0 && u < 10) {
            const int l = u >> 1;
            if ((u & 1) == 0) {
                // ======================= GEMM(l) =======================
                #pragma unroll
                for (int v = 0; v < NV; ++v)
                    #pragma unroll
                    for (int nt = 0; nt < 2; ++nt) acc[v][nt] = (f32x4){0.f, 0.f, 0.f, 0.f};

                const float* __restrict__ Wc =
                    (l == 0) ? W1 : (l == 1) ? W2 : (l == 2) ? W3 : (l == 3) ? W4 : W5;

                #pragma unroll
                for (int ks = 0; ks < 4; ++ks) {
                    // A frags (W hi/lo) for this ks only (no cross-ks hoist: R6 spilled)
                    f16x8 ah[2], al[2];
                    if (use_pre) {
                        #pragma unroll
                        for (int nt = 0; nt < 2; ++nt) {
                            const int f = ((l * 8 + (wn * 2 + nt)) * 4 + ks) * 64 + lane;
                            ah[nt] = *(const f16x8*)&whi[f * 8];
                            al[nt] = *(const f16x8*)&wlo[f * 8];
                        }
                    } else {
                        #pragma unroll
                        for (int nt = 0; nt < 2; ++nt) {
                            const int n  = (wn * 2 + nt) * 16 + l15;
                            const int k0 = ks * 32 + l4 * 8;
                            const float4 u0 = *(const float4*)&Wc[n * H + k0];
                            const float4 u1 = *(const float4*)&Wc[n * H + k0 + 4];
                            const float vv[8] = { u0.x, u0.y, u0.z, u0.w, u1.x, u1.y, u1.z, u1.w };
                            #pragma unroll
                            for (int e = 0; e < 8; ++e) {
                                _Float16 h_ = (_Float16)vv[e];
                                ah[nt][e] = h_;
                                al[nt][e] = (_Float16)(vv[e] - (float)h_);
                            }
                        }
                    }
                    // B frags: X hi/lo, col = point = l15, k = ks*32 + l4*8 + e
                    f16x8 xh[NV], xl[NV];
                    #pragma unroll
                    for (int v = 0; v < NV; ++v) {
                        const int base = (v * PG + l15) * XPAD + ks * 32 + l4 * 8;
                        xh[v] = *(const f16x8*)&myXhi[base];
                        xl[v] = *(const f16x8*)&myXlo[base];
                    }
                    __builtin_amdgcn_s_setprio(1);
                    #pragma unroll
                    for (int v = 0; v < NV; ++v)
                        #pragma unroll
                        for (int nt = 0; nt < 2; ++nt)
                            acc[v][nt] = __builtin_amdgcn_mfma_f32_16x16x32_f16(ah[nt], xh[v], acc[v][nt], 0, 0, 0);
                    #pragma unroll
                    for (int v = 0; v < NV; ++v)
                        #pragma unroll
                        for (int nt = 0; nt < 2; ++nt)
                            acc[v][nt] = __builtin_amdgcn_mfma_f32_16x16x32_f16(ah[nt], xl[v], acc[v][nt], 0, 0, 0);
                    #pragma unroll
                    for (int v = 0; v < NV; ++v)
                        #pragma unroll
                        for (int nt = 0; nt < 2; ++nt)
                            acc[v][nt] = __builtin_amdgcn_mfma_f32_16x16x32_f16(al[nt], xh[v], acc[v][nt], 0, 0, 0);
                    __builtin_amdgcn_s_setprio(0);
                }
            } else if (l < 4) {
                // ======================= EPI(l) ========================
                // D: col = point = l15, row = neuron n = (wn*2+nt)*16 + l4*4 + r
                const float* __restrict__ bc =
                    (l == 0) ? b1 : (l == 1) ? b2 : (l == 2) ? b3 : b4;
                #pragma unroll
                for (int nt = 0; nt < 2; ++nt) {
                    const int n0 = (wn * 2 + nt) * 16 + l4 * 4;
                    const float4 b4v = *(const float4*)&bc[n0];
                    const float bb[4] = { b4v.x, b4v.y, b4v.z, b4v.w };
                    float nv[NV][4];
                    #pragma unroll
                    for (int r = 0; r < 4; ++r) {
                        const float zv = acc[0][nt][r] + bb[r];
                        const float hv = fast_tanh(zv);
                        const float s  = 1.0f - hv * hv;
                        const float d0 = acc[1][nt][r], d1 = acc[2][nt][r];
                        const float d2 = acc[3][nt][r], d3 = acc[4][nt][r];
                        const float ssq = ((d0 * d0 - d1 * d1) - d2 * d2) - d3 * d3;
                        const float qn  = fmaf(s, acc[5][nt][r], -2.0f * hv * s * ssq);
                        nv[0][r] = hv;     nv[1][r] = s * d0; nv[2][r] = s * d1;
                        nv[3][r] = s * d2; nv[4][r] = s * d3; nv[5][r] = qn;
                    }
                    #pragma unroll
                    for (int v = 0; v < NV; ++v) {
                        const f16x2 h01 = pkrtz(nv[v][0], nv[v][1]);
                        const f16x2 h23 = pkrtz(nv[v][2], nv[v][3]);
                        const float o0 = nv[v][0] - (float)h01[0];
                        const float o1 = nv[v][1] - (float)h01[1];
                        const float o2 = nv[v][2] - (float)h23[0];
                        const float o3 = nv[v][3] - (float)h23[1];
                        const f16x2 o01 = pkrtz(o0, o1);
                        const f16x2 o23 = pkrtz(o2, o3);
                        const int off = (v * PG + l15) * XPAD + n0;
                        *(f16x4*)&myXhi[off] = __builtin_shufflevector(h01, h23, 0, 1, 2, 3);
                        *(f16x4*)&myXlo[off] = __builtin_shufflevector(o01, o23, 0, 1, 2, 3);
                    }
                }
            } else {
                // =================== head (l == 4) =====================
                float part = 0.0f;
                #pragma unroll
                for (int nt = 0; nt < 2; ++nt) {
                    const int n0 = (wn * 2 + nt) * 16 + l4 * 4;
                    const float4 b4v = *(const float4*)&b5[n0];
                    const float4 w6v = *(const float4*)&W6[n0];
                    const float bb[4] = { b4v.x, b4v.y, b4v.z, b4v.w };
                    const float ww[4] = { w6v.x, w6v.y, w6v.z, w6v.w };
                    #pragma unroll
                    for (int r = 0; r < 4; ++r) {
                        const float zv = acc[0][nt][r] + bb[r];
                        const float hv = fast_tanh(zv);
                        const float s  = 1.0f - hv * hv;
                        const float d0 = acc[1][nt][r], d1 = acc[2][nt][r];
                        const float d2 = acc[3][nt][r], d3 = acc[4][nt][r];
                        const float ssq = ((d0 * d0 - d1 * d1) - d2 * d2) - d3 * d3;
                        const float qf  = fmaf(s, acc[5][nt][r], -2.0f * hv * s * ssq);
                        part = fmaf(ww[r], qf, part);
                    }
                }
                // lanes {l15, l15+16, l15+32, l15+48}: different neurons, same point
                part += __shfl_xor(part, 16, 64);
                part += __shfl_xor(part, 32, 64);
                if (lane < 16) sRed[g][wn][lane] = part;
            }
        }
        __syncthreads();
    }

    if (tid < PB) {
        const int g2 = tid >> 4, p = tid & 15;
        const float rsum = sRed[g2][0][p] + sRed[g2][1][p] + sRed[g2][2][p] + sRed[g2][3][p];
        const int o = gb + tid;
        if (o < N) out[o] = rsum;
    }
}

extern "C" void kernel_launch(void* const* d_in, const int* in_sizes, int n_in,
                              void* d_out, int out_size, void* d_ws, size_t ws_size,
                              hipStream_t stream) {
    const float* t  = (const float*)d_in[0];
    const float* x  = (const float*)d_in[1];
    const float* y  = (const float*)d_in[2];
    const float* z  = (const float*)d_in[3];
    const float* W0 = (const float*)d_in[4];
    const float* b0 = (const float*)d_in[5];
    const float* W1 = (const float*)d_in[6];
    const float* b1 = (const float*)d_in[7];
    const float* W2 = (const float*)d_in[8];
    const float* b2 = (const float*)d_in[9];
    const float* W3 = (const float*)d_in[10];
    const float* b3 = (const float*)d_in[11];
    const float* W4 = (const float*)d_in[12];
    const float* b4 = (const float*)d_in[13];
    const float* W5 = (const float*)d_in[14];
    const float* b5 = (const float*)d_in[15];
    const float* W6 = (const float*)d_in[16];
    // d_in[17] = b6: unused (drops out of all derivatives)

    const int N = in_sizes[0];
    float* out = (float*)d_out;

    const int use_pre = (ws_size >= WS_NEEDED) ? 1 : 0;
    _Float16* whi = (_Float16*)d_ws;
    _Float16* wlo = whi + WFRAG_HALVES;

    if (use_pre) {
        presplit_w<<<(5 * 8 * 4 * 64) / 256, 256, 0, stream>>>(W1, W2, W3, W4, W5, whi, wlo);
    }
    const int grid = (N + PB - 1) / PB;
    pinn_mfma6<<<grid, TPB, 0, stream>>>(
        t, x, y, z, W0, b0, W1, b1, W2, b2, W3, b3, W4, b4, W5, b5, W6,
        whi, wlo, use_pre, out, N);
}

// Round 10
// 183.292 us; speedup vs baseline: 1.0822x; 1.0822x over previous
//
#include <hip/hip_runtime.h>
#include <hip/hip_fp16.h>
#include <math.h>

// PhysicsResidual via 2nd-order forward-mode AD, split-fp16 MFMA, operand-swapped.
// State per point: 6 vectors of 128 (h, 4 first derivs, q = signed 2nd-deriv combo).
// Per block: 16 points. Per layer GEMM: A = W (M=128 neurons), B = X^T (N = 6v*16p
// = 96 cols), K = 128. Split-fp16: A*B ~= Wh*Xh + Wh*Xl + Wl*Xh (fp32 MFMA acc).
// Fragment maps (validated R3/R4): arg0 row = lane&15, arg1 col = lane&15,
// k = (lane>>4)*8 + e; D: col = lane&15 (=point), row = (lane>>4)*4 + reg (=neuron).
// R10 = R8 (best: 178us, MfmaUtil 48, ~30% latency-idle) + 2-deep ping-pong
// prefetch of A-frags: A(ks+1) issued before MFMA(ks) cluster (700 cyc covers
// L2 latency); A(l+1,0) issued under EPI(l)'s VALU; A(0,0) under layer0.
// Named stage regs only (no runtime-indexed arrays -> no scratch, rule #20).
// NOT (256,3) launch_bounds (R6: forced spill); NOT split-phase (R9: -11%).

typedef _Float16 f16x8 __attribute__((ext_vector_type(8)));
typedef _Float16 f16x4 __attribute__((ext_vector_type(4)));
typedef _Float16 f16x2 __attribute__((ext_vector_type(2)));
typedef float    f32x4 __attribute__((ext_vector_type(4)));

constexpr int TPB  = 256;
constexpr int P    = 16;    // points per block
constexpr int H    = 128;
constexpr int XPAD = 136;   // halves per padded X row (272 B = 68 dw; 2-way-free banks)
constexpr int NV   = 6;
// pre-split W plane: 5 layers x 8 mt x 4 ks x 64 lanes x 8 halves
constexpr int WFRAG_HALVES = 5 * 8 * 4 * 64 * 8;           // 81920 halves
constexpr size_t WS_NEEDED = 2 * WFRAG_HALVES * sizeof(_Float16); // 327680 B

__device__ __forceinline__ float fast_tanh(float v) {
    float e = __expf(-2.0f * fabsf(v));
    float r = __builtin_amdgcn_rcpf(1.0f + e);
    return copysignf((1.0f - e) * r, v);
}

__device__ __forceinline__ f16x2 pkrtz(float a, float b) {
    return __builtin_bit_cast(f16x2, __builtin_amdgcn_cvt_pkrtz(a, b));
}

// ---------------- pre-split kernel: W1..W5 -> fp16 hi/lo fragments -----------
__global__ __launch_bounds__(256) void presplit_w(
    const float* __restrict__ W1, const float* __restrict__ W2,
    const float* __restrict__ W3, const float* __restrict__ W4,
    const float* __restrict__ W5, _Float16* __restrict__ whi,
    _Float16* __restrict__ wlo)
{
    const int gid = blockIdx.x * 256 + threadIdx.x;   // 0..10239
    const float* Ws[5] = { W1, W2, W3, W4, W5 };
    const int lane = gid & 63;
    const int rest = gid >> 6;        // 0..159
    const int ks   = rest & 3;
    const int mt   = (rest >> 2) & 7;
    const int l    = rest >> 5;       // 0..4
    const int n    = mt * 16 + (lane & 15);
    const int k0   = ks * 32 + (lane >> 4) * 8;
    const float4 u0 = *(const float4*)&Ws[l][n * H + k0];
    const float4 u1 = *(const float4*)&Ws[l][n * H + k0 + 4];
    const float vv[8] = { u0.x, u0.y, u0.z, u0.w, u1.x, u1.y, u1.z, u1.w };
    f16x8 h, o;
    #pragma unroll
    for (int e = 0; e < 8; ++e) {
        _Float16 hh = (_Float16)vv[e];
        h[e] = hh;
        o[e] = (_Float16)(vv[e] - (float)hh);
    }
    *(f16x8*)&whi[gid * 8] = h;
    *(f16x8*)&wlo[gid * 8] = o;
}

// ---------------- main kernel ------------------------------------------------
__global__ __launch_bounds__(TPB, 2) void pinn_mfma7(
    const float* __restrict__ t, const float* __restrict__ x,
    const float* __restrict__ y, const float* __restrict__ z,
    const float* __restrict__ W0, const float* __restrict__ b0,
    const float* __restrict__ W1, const float* __restrict__ b1,
    const float* __restrict__ W2, const float* __restrict__ b2,
    const float* __restrict__ W3, const float* __restrict__ b3,
    const float* __restrict__ W4, const float* __restrict__ b4,
    const float* __restrict__ W5, const float* __restrict__ b5,
    const float* __restrict__ W6,
    const _Float16* __restrict__ whi, const _Float16* __restrict__ wlo,
    int use_pre, float* __restrict__ out, int N)
{
    __shared__ _Float16 sXhi[NV * P * XPAD];   // 26112 B
    __shared__ _Float16 sXlo[NV * P * XPAD];   // 26112 B
    __shared__ float    sRed[4][P];            // 256 B -> 52480 B total

    const int tid  = threadIdx.x;
    const int lane = tid & 63;
    const int wn   = tid >> 6;     // wave 0..3: owns neuron tiles mt = wn*2 + nt
    const int l15  = lane & 15;
    const int l4   = lane >> 4;    // 0..3
    const int gb   = blockIdx.x * P;

    // ---- helpers (all compile-time indexed after unroll) -------------------
    f16x8 ahA[2], alA[2], ahB[2], alB[2];   // 2-deep A-frag ping-pong stages

    auto loadA = [&](int l, int ks, f16x8 ah[2], f16x8 al[2]) {
        #pragma unroll
        for (int nt = 0; nt < 2; ++nt) {
            const int f = ((l * 8 + (wn * 2 + nt)) * 4 + ks) * 64 + lane;
            ah[nt] = *(const f16x8*)&whi[f * 8];
            al[nt] = *(const f16x8*)&wlo[f * 8];
        }
    };

    // ---------------- prefetch A(layer1, ks0) — hides under layer0 ---------
    if (use_pre) loadA(0, 0, ahA, alA);

    // ---------------- layer 0 (input dim 4, analytic tangents) -------------
    {
        const int p0 = tid >> 4;          // 0..15
        const int i0 = tid & 15;          // owns neurons i0*8 .. i0*8+7
        int gp = gb + p0; if (gp >= N) gp = N - 1;
        const float pt0 = t[gp], pt1 = x[gp], pt2 = y[gp], pt3 = z[gp];
        float nv[NV][8];
        #pragma unroll
        for (int j = 0; j < 8; ++j) {
            const int i = i0 * 8 + j;
            const float4 wv = *(const float4*)&W0[i * 4];
            const float zv = fmaf(wv.x, pt0, fmaf(wv.y, pt1, fmaf(wv.z, pt2, fmaf(wv.w, pt3, b0[i]))));
            const float hv = fast_tanh(zv);
            const float s  = 1.0f - hv * hv;
            const float ssq = ((wv.x * wv.x - wv.y * wv.y) - wv.z * wv.z) - wv.w * wv.w;
            nv[0][j] = hv;       nv[1][j] = s * wv.x; nv[2][j] = s * wv.y;
            nv[3][j] = s * wv.z; nv[4][j] = s * wv.w; nv[5][j] = -2.0f * hv * s * ssq;
        }
        #pragma unroll
        for (int v = 0; v < NV; ++v) {
            f16x8 hh, oo;
            #pragma unroll
            for (int j = 0; j < 8; ++j) {
                _Float16 h_ = (_Float16)nv[v][j];
                hh[j] = h_;
                oo[j] = (_Float16)(nv[v][j] - (float)h_);
            }
            const int off = (v * P + p0) * XPAD + i0 * 8;
            *(f16x8*)&sXhi[off] = hh;
            *(f16x8*)&sXlo[off] = oo;
        }
    }

    for (int l = 0; l < 5; ++l) {
        __syncthreads();   // X(l) ready (layer0 or EPI(l-1) writes visible)

        f32x4 acc[NV][2];
        #pragma unroll
        for (int v = 0; v < NV; ++v)
            #pragma unroll
            for (int nt = 0; nt < 2; ++nt) acc[v][nt] = (f32x4){0.f, 0.f, 0.f, 0.f};

        auto mfma_cluster = [&](const f16x8 ah[2], const f16x8 al[2], int ks) {
            f16x8 xh[NV], xl[NV];
            #pragma unroll
            for (int v = 0; v < NV; ++v) {
                const int base = (v * P + l15) * XPAD + ks * 32 + l4 * 8;
                xh[v] = *(const f16x8*)&sXhi[base];
                xl[v] = *(const f16x8*)&sXlo[base];
            }
            __builtin_amdgcn_s_setprio(1);
            #pragma unroll
            for (int v = 0; v < NV; ++v)
                #pragma unroll
                for (int nt = 0; nt < 2; ++nt)
                    acc[v][nt] = __builtin_amdgcn_mfma_f32_16x16x32_f16(ah[nt], xh[v], acc[v][nt], 0, 0, 0);
            #pragma unroll
            for (int v = 0; v < NV; ++v)
                #pragma unroll
                for (int nt = 0; nt < 2; ++nt)
                    acc[v][nt] = __builtin_amdgcn_mfma_f32_16x16x32_f16(ah[nt], xl[v], acc[v][nt], 0, 0, 0);
            #pragma unroll
            for (int v = 0; v < NV; ++v)
                #pragma unroll
                for (int nt = 0; nt < 2; ++nt)
                    acc[v][nt] = __builtin_amdgcn_mfma_f32_16x16x32_f16(al[nt], xh[v], acc[v][nt], 0, 0, 0);
            __builtin_amdgcn_s_setprio(0);
        };

        if (use_pre) {
            // ahA/alA hold A(l,0): preloaded before layer0 (l=0) or under EPI(l-1)
            loadA(l, 1, ahB, alB);  mfma_cluster(ahA, alA, 0);
            loadA(l, 2, ahA, alA);  mfma_cluster(ahB, alB, 1);
            loadA(l, 3, ahB, alB);  mfma_cluster(ahA, alA, 2);
                                    mfma_cluster(ahB, alB, 3);
        } else {
            const float* __restrict__ Wc =
                (l == 0) ? W1 : (l == 1) ? W2 : (l == 2) ? W3 : (l == 3) ? W4 : W5;
            #pragma unroll
            for (int ks = 0; ks < 4; ++ks) {
                f16x8 ah[2], al[2];
                #pragma unroll
                for (int nt = 0; nt < 2; ++nt) {
                    const int n  = (wn * 2 + nt) * 16 + l15;
                    const int k0 = ks * 32 + l4 * 8;
                    const float4 u0 = *(const float4*)&Wc[n * H + k0];
                    const float4 u1 = *(const float4*)&Wc[n * H + k0 + 4];
                    const float vv[8] = { u0.x, u0.y, u0.z, u0.w, u1.x, u1.y, u1.z, u1.w };
                    #pragma unroll
                    for (int e = 0; e < 8; ++e) {
                        _Float16 h_ = (_Float16)vv[e];
                        ah[nt][e] = h_;
                        al[nt][e] = (_Float16)(vv[e] - (float)h_);
                    }
                }
                mfma_cluster(ah, al, ks);
            }
        }
        __syncthreads();   // all GEMM reads of sX complete before overwrite

        if (l < 4) {
            // prefetch A(l+1, ks0) — L2 latency hides under EPI's VALU
            if (use_pre) loadA(l + 1, 0, ahA, alA);
            // D: col = point = l15, row = neuron n = (wn*2+nt)*16 + l4*4 + r
            const float* __restrict__ bc =
                (l == 0) ? b1 : (l == 1) ? b2 : (l == 2) ? b3 : b4;
            #pragma unroll
            for (int nt = 0; nt < 2; ++nt) {
                const int n0 = (wn * 2 + nt) * 16 + l4 * 4;
                const float4 b4v = *(const float4*)&bc[n0];
                const float bb[4] = { b4v.x, b4v.y, b4v.z, b4v.w };
                float nv[NV][4];
                #pragma unroll
                for (int r = 0; r < 4; ++r) {
                    const float zv = acc[0][nt][r] + bb[r];
                    const float hv = fast_tanh(zv);
                    const float s  = 1.0f - hv * hv;
                    const float d0 = acc[1][nt][r], d1 = acc[2][nt][r];
                    const float d2 = acc[3][nt][r], d3 = acc[4][nt][r];
                    const float ssq = ((d0 * d0 - d1 * d1) - d2 * d2) - d3 * d3;
                    const float qn  = fmaf(s, acc[5][nt][r], -2.0f * hv * s * ssq);
                    nv[0][r] = hv;     nv[1][r] = s * d0; nv[2][r] = s * d1;
                    nv[3][r] = s * d2; nv[4][r] = s * d3; nv[5][r] = qn;
                }
                #pragma unroll
                for (int v = 0; v < NV; ++v) {
                    const f16x2 h01 = pkrtz(nv[v][0], nv[v][1]);
                    const f16x2 h23 = pkrtz(nv[v][2], nv[v][3]);
                    const float o0 = nv[v][0] - (float)h01[0];
                    const float o1 = nv[v][1] - (float)h01[1];
                    const float o2 = nv[v][2] - (float)h23[0];
                    const float o3 = nv[v][3] - (float)h23[1];
                    const f16x2 o01 = pkrtz(o0, o1);
                    const f16x2 o23 = pkrtz(o2, o3);
                    const int off = (v * P + l15) * XPAD + n0;
                    *(f16x4*)&sXhi[off] = __builtin_shufflevector(h01, h23, 0, 1, 2, 3);
                    *(f16x4*)&sXlo[off] = __builtin_shufflevector(o01, o23, 0, 1, 2, 3);
                }
            }
        } else {
            // last tanh layer + linear head fused: res = W6 . q_final
            float part = 0.0f;
            #pragma unroll
            for (int nt = 0; nt < 2; ++nt) {
                const int n0 = (wn * 2 + nt) * 16 + l4 * 4;
                const float4 b4v = *(const float4*)&b5[n0];
                const float4 w6v = *(const float4*)&W6[n0];
                const float bb[4] = { b4v.x, b4v.y, b4v.z, b4v.w };
                const float ww[4] = { w6v.x, w6v.y, w6v.z, w6v.w };
                #pragma unroll
                for (int r = 0; r < 4; ++r) {
                    const float zv = acc[0][nt][r] + bb[r];
                    const float hv = fast_tanh(zv);
                    const float s  = 1.0f - hv * hv;
                    const float d0 = acc[1][nt][r], d1 = acc[2][nt][r];
                    const float d2 = acc[3][nt][r], d3 = acc[4][nt][r];
                    const float ssq = ((d0 * d0 - d1 * d1) - d2 * d2) - d3 * d3;
                    const float qf  = fmaf(s, acc[5][nt][r], -2.0f * hv * s * ssq);
                    part = fmaf(ww[r], qf, part);
                }
            }
            // lanes {l15, l15+16, l15+32, l15+48}: different neurons, same point
            part += __shfl_xor(part, 16, 64);
            part += __shfl_xor(part, 32, 64);
            if (lane < 16) sRed[wn][lane] = part;
        }
    }

    __syncthreads();
    if (tid < P) {
        const float rsum = sRed[0][tid] + sRed[1][tid] + sRed[2][tid] + sRed[3][tid];
        const int o = gb + tid;
        if (o < N) out[o] = rsum;
    }
}

extern "C" void kernel_launch(void* const* d_in, const int* in_sizes, int n_in,
                              void* d_out, int out_size, void* d_ws, size_t ws_size,
                              hipStream_t stream) {
    const float* t  = (const float*)d_in[0];
    const float* x  = (const float*)d_in[1];
    const float* y  = (const float*)d_in[2];
    const float* z  = (const float*)d_in[3];
    const float* W0 = (const float*)d_in[4];
    const float* b0 = (const float*)d_in[5];
    const float* W1 = (const float*)d_in[6];
    const float* b1 = (const float*)d_in[7];
    const float* W2 = (const float*)d_in[8];
    const float* b2 = (const float*)d_in[9];
    const float* W3 = (const float*)d_in[10];
    const float* b3 = (const float*)d_in[11];
    const float* W4 = (const float*)d_in[12];
    const float* b4 = (const float*)d_in[13];
    const float* W5 = (const float*)d_in[14];
    const float* b5 = (const float*)d_in[15];
    const float* W6 = (const float*)d_in[16];
    // d_in[17] = b6: unused (drops out of all derivatives)

    const int N = in_sizes[0];
    float* out = (float*)d_out;

    const int use_pre = (ws_size >= WS_NEEDED) ? 1 : 0;
    _Float16* whi = (_Float16*)d_ws;
    _Float16* wlo = whi + WFRAG_HALVES;

    if (use_pre) {
        presplit_w<<<(5 * 8 * 4 * 64) / 256, 256, 0, stream>>>(W1, W2, W3, W4, W5, whi, wlo);
    }
    const int grid = (N + P - 1) / P;
    pinn_mfma7<<<grid, TPB, 0, stream>>>(
        t, x, y, z, W0, b0, W1, b1, W2, b2, W3, b3, W4, b4, W5, b5, W6,
        whi, wlo, use_pre, out, N);
}

// Round 11
// 176.859 us; speedup vs baseline: 1.1215x; 1.0364x over previous
//
#include <hip/hip_runtime.h>
#include <hip/hip_fp16.h>
#include <math.h>

// PhysicsResidual via 2nd-order forward-mode AD, split-fp16 MFMA, operand-swapped.
// State per point: 6 vectors of 128 (h, 4 first derivs, q = signed 2nd-deriv combo).
// Per block: 16 points. Per layer GEMM: A = W (M=128 neurons), B = X^T (N = 6v*16p
// = 96 cols), K = 128. Split-fp16: A*B ~= Wh*Xh + Wh*Xl + Wl*Xh (fp32 MFMA acc).
// Fragment maps (validated R3/R4): arg0 row = lane&15, arg1 col = lane&15,
// k = (lane>>4)*8 + e; D: col = lane&15 (=point), row = (lane>>4)*4 + reg (=neuron).
//
// R11 = R8 (best: 178us) + FRAGMENT-MAJOR X layout in LDS. R8's padded-row X gave
// 2.2e7 bank-conflict cycles (86Kcyc/CU = 20% of wall; LDS pipe 270K > MFMA 223K).
// X element [v][p][k] now lives at half-offset ((v*4 + k/32)*64 + p + 16*((k&31)>>3))*8
// + (k&7) — i.e. exactly the B-fragment order. GEMM reads become lane-contiguous
// 16B (zero-conflict); layer0 writes f16x8, epilogue writes f16x4, both uniform
// across banks. No padding -> LDS 49.4KB, still 3 blocks/CU.
// NOT (256,2)+prefetch (R10: occupancy 21%, -3%); NOT split-phase (R9); NOT
// cross-ks A-hoist (R6: scratch spill).

typedef _Float16 f16x8 __attribute__((ext_vector_type(8)));
typedef _Float16 f16x4 __attribute__((ext_vector_type(4)));
typedef _Float16 f16x2 __attribute__((ext_vector_type(2)));
typedef float    f32x4 __attribute__((ext_vector_type(4)));

constexpr int TPB  = 256;
constexpr int P    = 16;    // points per block
constexpr int H    = 128;
constexpr int NV   = 6;
constexpr int XFRAG_HALVES = NV * 4 * 64 * 8;   // 12288 halves = 24576 B per plane
// pre-split W plane: 5 layers x 8 mt x 4 ks x 64 lanes x 8 halves
constexpr int WFRAG_HALVES = 5 * 8 * 4 * 64 * 8;           // 81920 halves
constexpr size_t WS_NEEDED = 2 * WFRAG_HALVES * sizeof(_Float16); // 327680 B

__device__ __forceinline__ float fast_tanh(float v) {
    float e = __expf(-2.0f * fabsf(v));
    float r = __builtin_amdgcn_rcpf(1.0f + e);
    return copysignf((1.0f - e) * r, v);
}

__device__ __forceinline__ f16x2 pkrtz(float a, float b) {
    return __builtin_bit_cast(f16x2, __builtin_amdgcn_cvt_pkrtz(a, b));
}

// ---------------- pre-split kernel: W1..W5 -> fp16 hi/lo fragments -----------
__global__ __launch_bounds__(256) void presplit_w(
    const float* __restrict__ W1, const float* __restrict__ W2,
    const float* __restrict__ W3, const float* __restrict__ W4,
    const float* __restrict__ W5, _Float16* __restrict__ whi,
    _Float16* __restrict__ wlo)
{
    const int gid = blockIdx.x * 256 + threadIdx.x;   // 0..10239
    const float* Ws[5] = { W1, W2, W3, W4, W5 };
    const int lane = gid & 63;
    const int rest = gid >> 6;        // 0..159
    const int ks   = rest & 3;
    const int mt   = (rest >> 2) & 7;
    const int l    = rest >> 5;       // 0..4
    const int n    = mt * 16 + (lane & 15);
    const int k0   = ks * 32 + (lane >> 4) * 8;
    const float4 u0 = *(const float4*)&Ws[l][n * H + k0];
    const float4 u1 = *(const float4*)&Ws[l][n * H + k0 + 4];
    const float vv[8] = { u0.x, u0.y, u0.z, u0.w, u1.x, u1.y, u1.z, u1.w };
    f16x8 h, o;
    #pragma unroll
    for (int e = 0; e < 8; ++e) {
        _Float16 hh = (_Float16)vv[e];
        h[e] = hh;
        o[e] = (_Float16)(vv[e] - (float)hh);
    }
    *(f16x8*)&whi[gid * 8] = h;
    *(f16x8*)&wlo[gid * 8] = o;
}

// ---------------- main kernel ------------------------------------------------
__global__ __launch_bounds__(TPB, 3) void pinn_mfma8(
    const float* __restrict__ t, const float* __restrict__ x,
    const float* __restrict__ y, const float* __restrict__ z,
    const float* __restrict__ W0, const float* __restrict__ b0,
    const float* __restrict__ W1, const float* __restrict__ b1,
    const float* __restrict__ W2, const float* __restrict__ b2,
    const float* __restrict__ W3, const float* __restrict__ b3,
    const float* __restrict__ W4, const float* __restrict__ b4,
    const float* __restrict__ W5, const float* __restrict__ b5,
    const float* __restrict__ W6,
    const _Float16* __restrict__ whi, const _Float16* __restrict__ wlo,
    int use_pre, float* __restrict__ out, int N)
{
    __shared__ _Float16 sXhi[XFRAG_HALVES];    // 24576 B
    __shared__ _Float16 sXlo[XFRAG_HALVES];    // 24576 B
    __shared__ float    sRed[4][P];            // 256 B -> 49408 B total

    const int tid  = threadIdx.x;
    const int lane = tid & 63;
    const int wn   = tid >> 6;     // wave 0..3: owns neuron tiles mt = wn*2 + nt
    const int l15  = lane & 15;
    const int l4   = lane >> 4;    // 0..3
    const int gb   = blockIdx.x * P;

    // ---------------- layer 0 (input dim 4, analytic tangents) -------------
    {
        const int p0 = tid >> 4;          // 0..15
        const int i0 = tid & 15;          // owns neurons i0*8 .. i0*8+7
        int gp = gb + p0; if (gp >= N) gp = N - 1;
        const float pt0 = t[gp], pt1 = x[gp], pt2 = y[gp], pt3 = z[gp];
        float nv[NV][8];
        #pragma unroll
        for (int j = 0; j < 8; ++j) {
            const int i = i0 * 8 + j;
            const float4 wv = *(const float4*)&W0[i * 4];
            const float zv = fmaf(wv.x, pt0, fmaf(wv.y, pt1, fmaf(wv.z, pt2, fmaf(wv.w, pt3, b0[i]))));
            const float hv = fast_tanh(zv);
            const float s  = 1.0f - hv * hv;
            const float ssq = ((wv.x * wv.x - wv.y * wv.y) - wv.z * wv.z) - wv.w * wv.w;
            nv[0][j] = hv;       nv[1][j] = s * wv.x; nv[2][j] = s * wv.y;
            nv[3][j] = s * wv.z; nv[4][j] = s * wv.w; nv[5][j] = -2.0f * hv * s * ssq;
        }
        // frag-major: element [v][p][k=i0*8+j] -> frag(v, i0>>2), lane p+16*(i0&3), e=j
        #pragma unroll
        for (int v = 0; v < NV; ++v) {
            f16x8 hh, oo;
            #pragma unroll
            for (int j = 0; j < 8; ++j) {
                _Float16 h_ = (_Float16)nv[v][j];
                hh[j] = h_;
                oo[j] = (_Float16)(nv[v][j] - (float)h_);
            }
            const int off = ((v * 4 + (i0 >> 2)) * 64 + p0 + 16 * (i0 & 3)) * 8;
            *(f16x8*)&sXhi[off] = hh;
            *(f16x8*)&sXlo[off] = oo;
        }
    }
    __syncthreads();

    for (int l = 0; l < 5; ++l) {
        f32x4 acc[NV][2];
        #pragma unroll
        for (int v = 0; v < NV; ++v)
            #pragma unroll
            for (int nt = 0; nt < 2; ++nt) acc[v][nt] = (f32x4){0.f, 0.f, 0.f, 0.f};

        const float* __restrict__ Wc =
            (l == 0) ? W1 : (l == 1) ? W2 : (l == 2) ? W3 : (l == 3) ? W4 : W5;

        #pragma unroll
        for (int ks = 0; ks < 4; ++ks) {
            // A frags (W hi/lo) for this ks only (NO cross-ks hoist: R6 spilled)
            f16x8 ah[2], al[2];
            if (use_pre) {
                #pragma unroll
                for (int nt = 0; nt < 2; ++nt) {
                    const int f = ((l * 8 + (wn * 2 + nt)) * 4 + ks) * 64 + lane;
                    ah[nt] = *(const f16x8*)&whi[f * 8];
                    al[nt] = *(const f16x8*)&wlo[f * 8];
                }
            } else {
                #pragma unroll
                for (int nt = 0; nt < 2; ++nt) {
                    const int n  = (wn * 2 + nt) * 16 + l15;
                    const int k0 = ks * 32 + l4 * 8;
                    const float4 u0 = *(const float4*)&Wc[n * H + k0];
                    const float4 u1 = *(const float4*)&Wc[n * H + k0 + 4];
                    const float vv[8] = { u0.x, u0.y, u0.z, u0.w, u1.x, u1.y, u1.z, u1.w };
                    #pragma unroll
                    for (int e = 0; e < 8; ++e) {
                        _Float16 h_ = (_Float16)vv[e];
                        ah[nt][e] = h_;
                        al[nt][e] = (_Float16)(vv[e] - (float)h_);
                    }
                }
            }
            // B frags: lane-contiguous 16B reads (zero-conflict by construction)
            f16x8 xh[NV], xl[NV];
            #pragma unroll
            for (int v = 0; v < NV; ++v) {
                const int base = ((v * 4 + ks) * 64 + lane) * 8;
                xh[v] = *(const f16x8*)&sXhi[base];
                xl[v] = *(const f16x8*)&sXlo[base];
            }
            __builtin_amdgcn_s_setprio(1);
            #pragma unroll
            for (int v = 0; v < NV; ++v)
                #pragma unroll
                for (int nt = 0; nt < 2; ++nt)
                    acc[v][nt] = __builtin_amdgcn_mfma_f32_16x16x32_f16(ah[nt], xh[v], acc[v][nt], 0, 0, 0);
            #pragma unroll
            for (int v = 0; v < NV; ++v)
                #pragma unroll
                for (int nt = 0; nt < 2; ++nt)
                    acc[v][nt] = __builtin_amdgcn_mfma_f32_16x16x32_f16(ah[nt], xl[v], acc[v][nt], 0, 0, 0);
            #pragma unroll
            for (int v = 0; v < NV; ++v)
                #pragma unroll
                for (int nt = 0; nt < 2; ++nt)
                    acc[v][nt] = __builtin_amdgcn_mfma_f32_16x16x32_f16(al[nt], xh[v], acc[v][nt], 0, 0, 0);
            __builtin_amdgcn_s_setprio(0);
        }
        __syncthreads();   // all GEMM reads of sX complete before overwrite

        if (l < 4) {
            // D: col = point = l15, row = neuron n = (wn*2+nt)*16 + l4*4 + r
            const float* __restrict__ bc =
                (l == 0) ? b1 : (l == 1) ? b2 : (l == 2) ? b3 : b4;
            #pragma unroll
            for (int nt = 0; nt < 2; ++nt) {
                const int n0  = (wn * 2 + nt) * 16 + l4 * 4;
                const int ksp = n0 >> 5;            // next-layer frag ks
                const int l4p = (n0 & 31) >> 3;     // k-subgroup
                const int e0  = n0 & 7;             // 0 or 4
                const float4 b4v = *(const float4*)&bc[n0];
                const float bb[4] = { b4v.x, b4v.y, b4v.z, b4v.w };
                float nv[NV][4];
                #pragma unroll
                for (int r = 0; r < 4; ++r) {
                    const float zv = acc[0][nt][r] + bb[r];
                    const float hv = fast_tanh(zv);
                    const float s  = 1.0f - hv * hv;
                    const float d0 = acc[1][nt][r], d1 = acc[2][nt][r];
                    const float d2 = acc[3][nt][r], d3 = acc[4][nt][r];
                    const float ssq = ((d0 * d0 - d1 * d1) - d2 * d2) - d3 * d3;
                    const float qn  = fmaf(s, acc[5][nt][r], -2.0f * hv * s * ssq);
                    nv[0][r] = hv;     nv[1][r] = s * d0; nv[2][r] = s * d1;
                    nv[3][r] = s * d2; nv[4][r] = s * d3; nv[5][r] = qn;
                }
                #pragma unroll
                for (int v = 0; v < NV; ++v) {
                    const f16x2 h01 = pkrtz(nv[v][0], nv[v][1]);
                    const f16x2 h23 = pkrtz(nv[v][2], nv[v][3]);
                    const float o0 = nv[v][0] - (float)h01[0];
                    const float o1 = nv[v][1] - (float)h01[1];
                    const float o2 = nv[v][2] - (float)h23[0];
                    const float o3 = nv[v][3] - (float)h23[1];
                    const f16x2 o01 = pkrtz(o0, o1);
                    const f16x2 o23 = pkrtz(o2, o3);
                    // frag-major: [v][p=l15][k=n0+r] -> frag(v,ksp), lane l15+16*l4p, e=e0+r
                    const int off = ((v * 4 + ksp) * 64 + l15 + 16 * l4p) * 8 + e0;
                    *(f16x4*)&sXhi[off] = __builtin_shufflevector(h01, h23, 0, 1, 2, 3);
                    *(f16x4*)&sXlo[off] = __builtin_shufflevector(o01, o23, 0, 1, 2, 3);
                }
            }
            __syncthreads();
        } else {
            // last tanh layer + linear head fused: res = W6 . q_final
            float part = 0.0f;
            #pragma unroll
            for (int nt = 0; nt < 2; ++nt) {
                const int n0 = (wn * 2 + nt) * 16 + l4 * 4;
                const float4 b4v = *(const float4*)&b5[n0];
                const float4 w6v = *(const float4*)&W6[n0];
                const float bb[4] = { b4v.x, b4v.y, b4v.z, b4v.w };
                const float ww[4] = { w6v.x, w6v.y, w6v.z, w6v.w };
                #pragma unroll
                for (int r = 0; r < 4; ++r) {
                    const float zv = acc[0][nt][r] + bb[r];
                    const float hv = fast_tanh(zv);
                    const float s  = 1.0f - hv * hv;
                    const float d0 = acc[1][nt][r], d1 = acc[2][nt][r];
                    const float d2 = acc[3][nt][r], d3 = acc[4][nt][r];
                    const float ssq = ((d0 * d0 - d1 * d1) - d2 * d2) - d3 * d3;
                    const float qf  = fmaf(s, acc[5][nt][r], -2.0f * hv * s * ssq);
                    part = fmaf(ww[r], qf, part);
                }
            }
            // lanes {l15, l15+16, l15+32, l15+48}: different neurons, same point
            part += __shfl_xor(part, 16, 64);
            part += __shfl_xor(part, 32, 64);
            if (lane < 16) sRed[wn][lane] = part;
        }
    }

    __syncthreads();
    if (tid < P) {
        const float rsum = sRed[0][tid] + sRed[1][tid] + sRed[2][tid] + sRed[3][tid];
        const int o = gb + tid;
        if (o < N) out[o] = rsum;
    }
}

extern "C" void kernel_launch(void* const* d_in, const int* in_sizes, int n_in,
                              void* d_out, int out_size, void* d_ws, size_t ws_size,
                              hipStream_t stream) {
    const float* t  = (const float*)d_in[0];
    const float* x  = (const float*)d_in[1];
    const float* y  = (const float*)d_in[2];
    const float* z  = (const float*)d_in[3];
    const float* W0 = (const float*)d_in[4];
    const float* b0 = (const float*)d_in[5];
    const float* W1 = (const float*)d_in[6];
    const float* b1 = (const float*)d_in[7];
    const float* W2 = (const float*)d_in[8];
    const float* b2 = (const float*)d_in[9];
    const float* W3 = (const float*)d_in[10];
    const float* b3 = (const float*)d_in[11];
    const float* W4 = (const float*)d_in[12];
    const float* b4 = (const float*)d_in[13];
    const float* W5 = (const float*)d_in[14];
    const float* b5 = (const float*)d_in[15];
    const float* W6 = (const float*)d_in[16];
    // d_in[17] = b6: unused (drops out of all derivatives)

    const int N = in_sizes[0];
    float* out = (float*)d_out;

    const int use_pre = (ws_size >= WS_NEEDED) ? 1 : 0;
    _Float16* whi = (_Float16*)d_ws;
    _Float16* wlo = whi + WFRAG_HALVES;

    if (use_pre) {
        presplit_w<<<(5 * 8 * 4 * 64) / 256, 256, 0, stream>>>(W1, W2, W3, W4, W5, whi, wlo);
    }
    const int grid = (N + P - 1) / P;
    pinn_mfma8<<<grid, TPB, 0, stream>>>(
        t, x, y, z, W0, b0, W1, b1, W2, b2, W3, b3, W4, b4, W5, b5, W6,
        whi, wlo, use_pre, out, N);
}